// Round 1
// baseline (622.371 us; speedup 1.0000x reference)
//
#include <hip/hip_runtime.h>
#include <stdint.h>

#define N_NODES 40000
#define N_EDGES 640000
#define DD 128
#define LAYERS 3

// ---------------- CSR build ----------------

__global__ void count_deg_kernel(const int* __restrict__ dst, int* __restrict__ deg) {
  int e = blockIdx.x * blockDim.x + threadIdx.x;
  if (e < N_EDGES) atomicAdd(&deg[dst[e]], 1);
}

__global__ __launch_bounds__(1024) void scan_kernel(const int* __restrict__ deg,
                                                    int* __restrict__ offs) {
  __shared__ int sums[1024];
  const int CH = 40;  // 1024*40 = 40960 >= 40000
  int t = threadIdx.x;
  int base = t * CH;
  int vals[CH];
  int local = 0;
#pragma unroll
  for (int i = 0; i < CH; ++i) {
    int idx = base + i;
    int d = (idx < N_NODES) ? deg[idx] : 0;
    vals[i] = local;
    local += d;
  }
  int mytot = local;
  sums[t] = local;
  __syncthreads();
  for (int off = 1; off < 1024; off <<= 1) {
    int v = (t >= off) ? sums[t - off] : 0;
    __syncthreads();
    sums[t] += v;
    __syncthreads();
  }
  int prefix = sums[t] - mytot;
#pragma unroll
  for (int i = 0; i < CH; ++i) {
    int idx = base + i;
    if (idx < N_NODES) offs[idx] = prefix + vals[i];
  }
  if (t == 0) offs[N_NODES] = sums[1023];
}

__global__ void invdeg_kernel(const int* __restrict__ deg, float* __restrict__ inv_deg) {
  int i = blockIdx.x * blockDim.x + threadIdx.x;
  if (i < N_NODES) {
    int d = deg[i];
    inv_deg[i] = 1.0f / (float)(d > 1 ? d : 1);
  }
}

__global__ void fill_csr_kernel(const int* __restrict__ src, const int* __restrict__ dst,
                                const int* __restrict__ offs, int* __restrict__ cnt,
                                int* __restrict__ csr) {
  int e = blockIdx.x * blockDim.x + threadIdx.x;
  if (e < N_EDGES) {
    int d = dst[e];
    int pos = offs[d] + atomicAdd(&cnt[d], 1);
    csr[pos] = src[e];
  }
}

// ---------------- node GEMM: out[M x 128] = act(X[M x K] @ W[K x 128] + bias) (+res) ----
// X is given as two pointers (k<128 -> X0, k>=128 -> X1), both row-stride 128.
// M = 40000, divisible by BM=64 -> no bounds checks.

template <int K, bool RELU, bool RES>
__global__ __launch_bounds__(256) void gemm_node(const float* __restrict__ X0,
                                                 const float* __restrict__ X1,
                                                 const float* __restrict__ W,
                                                 const float* __restrict__ bias,
                                                 const float* __restrict__ res,
                                                 float* __restrict__ out) {
  __shared__ float Xs[32][64];    // 8 KB  (transposed: Xs[k][row])
  __shared__ float Ws[32][128];   // 16 KB
  const int tid = threadIdx.x;
  const int row0 = blockIdx.x * 64;
  const int tr = (tid >> 4) * 4;  // local row base (0..60)
  const int tc = (tid & 15) * 8;  // local col base (0..120)

  float acc[4][8];
#pragma unroll
  for (int i = 0; i < 4; ++i)
#pragma unroll
    for (int j = 0; j < 8; ++j) acc[i][j] = 0.f;

  for (int k0 = 0; k0 < K; k0 += 32) {
    const float* Xp = (K == 128 || k0 < 128) ? (X0 + k0) : (X1 + (k0 - 128));
    // X tile: 64 rows x 32 k -> 512 float4, 2 per thread
#pragma unroll
    for (int i = 0; i < 2; ++i) {
      int fi = tid + i * 256;
      int r = fi >> 3;
      int k4 = (fi & 7) * 4;
      float4 v = *(const float4*)(Xp + (size_t)(row0 + r) * DD + k4);
      Xs[k4 + 0][r] = v.x;
      Xs[k4 + 1][r] = v.y;
      Xs[k4 + 2][r] = v.z;
      Xs[k4 + 3][r] = v.w;
    }
    // W tile: 32 k x 128 n -> 1024 float4, 4 per thread
#pragma unroll
    for (int i = 0; i < 4; ++i) {
      int fi = tid + i * 256;
      int kk = fi >> 5;
      int n4 = (fi & 31) * 4;
      *(float4*)(&Ws[kk][n4]) = *(const float4*)(W + (size_t)(k0 + kk) * DD + n4);
    }
    __syncthreads();
#pragma unroll
    for (int kk = 0; kk < 32; ++kk) {
      float xr[4], wc[8];
      *(float4*)xr = *(const float4*)(&Xs[kk][tr]);
      *(float4*)(wc) = *(const float4*)(&Ws[kk][tc]);
      *(float4*)(wc + 4) = *(const float4*)(&Ws[kk][tc + 4]);
#pragma unroll
      for (int i = 0; i < 4; ++i)
#pragma unroll
        for (int j = 0; j < 8; ++j) acc[i][j] = fmaf(xr[i], wc[j], acc[i][j]);
    }
    __syncthreads();
  }

  // epilogue
  float bj[8];
  if (bias) {
    *(float4*)bj = *(const float4*)(bias + tc);
    *(float4*)(bj + 4) = *(const float4*)(bias + tc + 4);
  } else {
#pragma unroll
    for (int j = 0; j < 8; ++j) bj[j] = 0.f;
  }
#pragma unroll
  for (int i = 0; i < 4; ++i) {
    size_t grow = (size_t)(row0 + tr + i) * DD;
    float v[8];
#pragma unroll
    for (int j = 0; j < 8; ++j) {
      v[j] = acc[i][j] + bj[j];
      if (RELU) v[j] = fmaxf(v[j], 0.f);
    }
    if (RES) {
      float r0[8];
      *(float4*)r0 = *(const float4*)(res + grow + tc);
      *(float4*)(r0 + 4) = *(const float4*)(res + grow + tc + 4);
#pragma unroll
      for (int j = 0; j < 8; ++j) v[j] += r0[j];
    }
    *(float4*)(out + grow + tc) = *(const float4*)(v);
    *(float4*)(out + grow + tc + 4) = *(const float4*)(v + 4);
  }
}

// ---------------- aggregation: agg[i] = inv_deg[i] * sum_e relu(A[i] + B[src_e]) ----
// one wave per node, lane handles 2 channels (float2)

__global__ __launch_bounds__(256) void aggregate_kernel(const float* __restrict__ A,
                                                        const float* __restrict__ B,
                                                        const int* __restrict__ offs,
                                                        const int* __restrict__ csr,
                                                        const float* __restrict__ inv_deg,
                                                        float* __restrict__ agg) {
  int node = blockIdx.x * 4 + (threadIdx.x >> 6);
  if (node >= N_NODES) return;
  int lane = threadIdx.x & 63;
  const int c = lane * 2;
  float2 a = *(const float2*)(A + (size_t)node * DD + c);
  float ax = a.x, ay = a.y;
  int beg = offs[node], end = offs[node + 1];
  float sx = 0.f, sy = 0.f;
  int e = beg;
  for (; e + 4 <= end; e += 4) {
    int s0 = csr[e + 0], s1 = csr[e + 1], s2 = csr[e + 2], s3 = csr[e + 3];
    float2 b0 = *(const float2*)(B + (size_t)s0 * DD + c);
    float2 b1 = *(const float2*)(B + (size_t)s1 * DD + c);
    float2 b2 = *(const float2*)(B + (size_t)s2 * DD + c);
    float2 b3 = *(const float2*)(B + (size_t)s3 * DD + c);
    sx += fmaxf(ax + b0.x, 0.f);
    sy += fmaxf(ay + b0.y, 0.f);
    sx += fmaxf(ax + b1.x, 0.f);
    sy += fmaxf(ay + b1.y, 0.f);
    sx += fmaxf(ax + b2.x, 0.f);
    sy += fmaxf(ay + b2.y, 0.f);
    sx += fmaxf(ax + b3.x, 0.f);
    sy += fmaxf(ay + b3.y, 0.f);
  }
  for (; e < end; ++e) {
    int s = csr[e];
    float2 b = *(const float2*)(B + (size_t)s * DD + c);
    sx += fmaxf(ax + b.x, 0.f);
    sy += fmaxf(ay + b.y, 0.f);
  }
  float w = inv_deg[node];
  float2 r;
  r.x = sx * w;
  r.y = sy * w;
  *(float2*)(agg + (size_t)node * DD + c) = r;
}

// ---------------- launch ----------------

static inline char* align256(char* p) {
  return (char*)(((uintptr_t)p + 255) & ~(uintptr_t)255);
}

extern "C" void kernel_launch(void* const* d_in, const int* in_sizes, int n_in,
                              void* d_out, int out_size, void* d_ws, size_t ws_size,
                              hipStream_t stream) {
  const float* x_in  = (const float*)d_in[0];
  const int*   ei    = (const int*)d_in[1];     // [2, E] int32: row0 = src, row1 = dst
  const float* psi_w = (const float*)d_in[2];   // [3, 256, 128]
  const float* psi_b = (const float*)d_in[3];   // [3, 128]
  const float* phi_w = (const float*)d_in[4];   // [3, 256, 128]
  const float* phi_b = (const float*)d_in[5];   // [3, 128]
  const float* dp_w  = (const float*)d_in[6];   // [128, 128]
  const float* dp_b  = (const float*)d_in[7];   // [128]
  float* out = (float*)d_out;

  const int* e_src = ei;
  const int* e_dst = ei + N_EDGES;

  // workspace carve
  char* p = (char*)d_ws;
  int* deg = (int*)p;                 p = align256(p + N_NODES * sizeof(int));
  int* cnt = (int*)p;                 p = align256(p + N_NODES * sizeof(int));
  int* offs = (int*)p;                p = align256(p + (N_NODES + 1) * sizeof(int));
  int* csr = (int*)p;                 p = align256(p + N_EDGES * sizeof(int));
  float* inv_deg = (float*)p;         p = align256(p + N_NODES * sizeof(float));
  float* Abuf = (float*)p;            p = align256(p + (size_t)N_NODES * DD * sizeof(float));
  float* Bbuf = (float*)p;            p = align256(p + (size_t)N_NODES * DD * sizeof(float));
  float* aggbuf = (float*)p;          p = align256(p + (size_t)N_NODES * DD * sizeof(float));
  float* X0 = (float*)p;              p = align256(p + (size_t)N_NODES * DD * sizeof(float));

  hipMemsetAsync(deg, 0, N_NODES * sizeof(int), stream);
  hipMemsetAsync(cnt, 0, N_NODES * sizeof(int), stream);

  const int EB = 256;
  count_deg_kernel<<<(N_EDGES + EB - 1) / EB, EB, 0, stream>>>(e_dst, deg);
  scan_kernel<<<1, 1024, 0, stream>>>(deg, offs);
  invdeg_kernel<<<(N_NODES + EB - 1) / EB, EB, 0, stream>>>(deg, inv_deg);
  fill_csr_kernel<<<(N_EDGES + EB - 1) / EB, EB, 0, stream>>>(e_src, e_dst, offs, cnt, csr);

  const int GB = N_NODES / 64;  // 625 blocks
  const int AGB = (N_NODES + 3) / 4;

  const float* xc = x_in;
  for (int l = 0; l < LAYERS; ++l) {
    const float* pw = psi_w + (size_t)l * 256 * DD;
    // A = x @ psi_w[0:128] + psi_b   ;   B = x @ psi_w[128:256]
    gemm_node<128, false, false><<<GB, 256, 0, stream>>>(xc, nullptr, pw, psi_b + l * DD,
                                                         nullptr, Abuf);
    gemm_node<128, false, false><<<GB, 256, 0, stream>>>(xc, nullptr, pw + 128 * DD, nullptr,
                                                         nullptr, Bbuf);
    aggregate_kernel<<<AGB, 256, 0, stream>>>(Abuf, Bbuf, offs, csr, inv_deg, aggbuf);
    // new_x = relu(cat[x, agg] @ phi_w + phi_b) + x
    float* xn = (l == 1) ? out : X0;  // l0 -> X0, l1 -> out, l2 -> X0
    gemm_node<256, true, true><<<GB, 256, 0, stream>>>(xc, aggbuf,
                                                       phi_w + (size_t)l * 256 * DD,
                                                       phi_b + l * DD, xc, xn);
    xc = xn;
  }
  // final: out = x @ dp_w + dp_b
  gemm_node<128, false, false><<<GB, 256, 0, stream>>>(xc, nullptr, dp_w, dp_b, nullptr, out);
}

// Round 2
// 388.477 us; speedup vs baseline: 1.6021x; 1.6021x over previous
//
#include <hip/hip_runtime.h>
#include <stdint.h>

#define N_NODES 40000
#define N_EDGES 640000
#define DD 128
#define LAYERS 3

typedef unsigned short u16;
typedef u16 u16x8 __attribute__((ext_vector_type(8)));
typedef short bf16x8 __attribute__((ext_vector_type(8)));   // 8 bf16 (4 VGPRs)
typedef float f32x4 __attribute__((ext_vector_type(4)));

__device__ inline u16 f2bf(float f) {  // RNE f32 -> bf16 (finite inputs)
  uint32_t u = __float_as_uint(f);
  return (u16)((u + 0x7fffu + ((u >> 16) & 1u)) >> 16);
}
__device__ inline float bflo2f(uint32_t u) { return __uint_as_float(u << 16); }
__device__ inline float bfhi2f(uint32_t u) { return __uint_as_float(u & 0xffff0000u); }

// ---------------- CSR build ----------------

__global__ void count_deg_kernel(const int* __restrict__ dst, int* __restrict__ deg) {
  int e = blockIdx.x * blockDim.x + threadIdx.x;
  if (e < N_EDGES) atomicAdd(&deg[dst[e]], 1);
}

__global__ __launch_bounds__(1024) void scan_kernel(const int* __restrict__ deg,
                                                    int* __restrict__ offs) {
  __shared__ int sums[1024];
  const int CH = 40;  // 1024*40 = 40960 >= 40000
  int t = threadIdx.x;
  int base = t * CH;
  int vals[CH];
  int local = 0;
#pragma unroll
  for (int i = 0; i < CH; ++i) {
    int idx = base + i;
    int d = (idx < N_NODES) ? deg[idx] : 0;
    vals[i] = local;
    local += d;
  }
  int mytot = local;
  sums[t] = local;
  __syncthreads();
  for (int off = 1; off < 1024; off <<= 1) {
    int v = (t >= off) ? sums[t - off] : 0;
    __syncthreads();
    sums[t] += v;
    __syncthreads();
  }
  int prefix = sums[t] - mytot;
#pragma unroll
  for (int i = 0; i < CH; ++i) {
    int idx = base + i;
    if (idx < N_NODES) offs[idx] = prefix + vals[i];
  }
  if (t == 0) offs[N_NODES] = sums[1023];
}

__global__ void invdeg_kernel(const int* __restrict__ deg, float* __restrict__ inv_deg) {
  int i = blockIdx.x * blockDim.x + threadIdx.x;
  if (i < N_NODES) {
    int d = deg[i];
    inv_deg[i] = 1.0f / (float)(d > 1 ? d : 1);
  }
}

__global__ void fill_csr_kernel(const int* __restrict__ src, const int* __restrict__ dst,
                                const int* __restrict__ offs, int* __restrict__ cnt,
                                int* __restrict__ csr) {
  int e = blockIdx.x * blockDim.x + threadIdx.x;
  if (e < N_EDGES) {
    int d = dst[e];
    int pos = offs[d] + atomicAdd(&cnt[d], 1);
    csr[pos] = src[e];
  }
}

// ---------------- conversions ----------------

__global__ void convert_x_kernel(const float* __restrict__ x, u16* __restrict__ xb) {
  size_t i = (size_t)(blockIdx.x * blockDim.x + threadIdx.x) * 8;  // 5.12M elems, grid covers exactly
  float4 v0 = *(const float4*)(x + i);
  float4 v1 = *(const float4*)(x + i + 4);
  u16x8 o;
  o[0] = f2bf(v0.x); o[1] = f2bf(v0.y); o[2] = f2bf(v0.z); o[3] = f2bf(v0.w);
  o[4] = f2bf(v1.x); o[5] = f2bf(v1.y); o[6] = f2bf(v1.z); o[7] = f2bf(v1.w);
  *(u16x8*)(xb + i) = o;
}

// transpose+convert all weights: psiT/phiT: [l][n=128][k=256]; dpT: [n=128][k=128]
__global__ void convert_w_kernel(const float* __restrict__ psi_w, const float* __restrict__ phi_w,
                                 const float* __restrict__ dp_w, u16* __restrict__ psiT,
                                 u16* __restrict__ phiT, u16* __restrict__ dpT) {
  int idx = blockIdx.x * blockDim.x + threadIdx.x;
  if (idx < 98304) {
    int l = idx >> 15, r = idx & 32767, n = r >> 8, k = r & 255;
    psiT[idx] = f2bf(psi_w[l * 32768 + k * 128 + n]);
  } else if (idx < 196608) {
    int j = idx - 98304;
    int l = j >> 15, r = j & 32767, n = r >> 8, k = r & 255;
    phiT[j] = f2bf(phi_w[l * 32768 + k * 128 + n]);
  } else if (idx < 212992) {
    int j = idx - 196608;
    int n = j >> 7, k = j & 127;
    dpT[j] = f2bf(dp_w[k * 128 + n]);
  }
}

// ---------------- MFMA GEMM: out[M x 128] = act(X[M x K] @ W + bias) (+res) ----
// X given as bf16, row-stride 128; for K=256 second half comes from X1.
// Wt: bf16 [n=128][k], row stride WS (pointer may be pre-offset into k).
// Block: 64 rows x 128 cols, 4 waves; wave w -> rows [w*16, w*16+16), all 128 cols.

template <int K, int WS, bool RELU, bool RES, bool WF, bool WB>
__global__ __launch_bounds__(256, 4) void gemm_mfma(
    const u16* __restrict__ X0, const u16* __restrict__ X1, const u16* __restrict__ Wt,
    const float* __restrict__ bias, const float* __restrict__ res, float* __restrict__ out,
    u16* __restrict__ outb) {
  __shared__ u16 Xs[64][72];    // +8 pad: fragment reads alias only 2-way (free)
  __shared__ u16 Ws[128][72];
  const int tid = threadIdx.x;
  const int row0 = blockIdx.x * 64;
  const int w = tid >> 6, lane = tid & 63;
  const int lm = lane & 15, lq = lane >> 4;

  f32x4 acc[8];
#pragma unroll
  for (int i = 0; i < 8; ++i) acc[i] = (f32x4){0.f, 0.f, 0.f, 0.f};

  const int NCH = K / 64;
#pragma unroll
  for (int c = 0; c < NCH; ++c) {
    const u16* Xsrc = (K == 256 && c >= 2) ? (X1 + (c - 2) * 64) : (X0 + c * 64);
    // X tile: 64 rows x 64 k -> 512 x 16B, 2/thread
#pragma unroll
    for (int i = 0; i < 2; ++i) {
      int fi = tid + i * 256;
      int r = fi >> 3, k8 = (fi & 7) * 8;
      *(u16x8*)&Xs[r][k8] = *(const u16x8*)(Xsrc + (size_t)(row0 + r) * DD + k8);
    }
    // W tile: 128 n x 64 k -> 1024 x 16B, 4/thread
#pragma unroll
    for (int i = 0; i < 4; ++i) {
      int fi = tid + i * 256;
      int n = fi >> 3, k8 = (fi & 7) * 8;
      *(u16x8*)&Ws[n][k8] = *(const u16x8*)(Wt + (size_t)n * WS + c * 64 + k8);
    }
    __syncthreads();
#pragma unroll
    for (int ks = 0; ks < 2; ++ks) {
      bf16x8 a = *(const bf16x8*)&Xs[w * 16 + lm][lq * 8 + ks * 32];
#pragma unroll
      for (int nt = 0; nt < 8; ++nt) {
        bf16x8 b = *(const bf16x8*)&Ws[nt * 16 + lm][lq * 8 + ks * 32];
        acc[nt] = __builtin_amdgcn_mfma_f32_16x16x32_bf16(a, b, acc[nt], 0, 0, 0);
      }
    }
    __syncthreads();
  }

  // epilogue: C/D layout col=lane&15, row=lq*4+reg
  float bj[8];
#pragma unroll
  for (int nt = 0; nt < 8; ++nt) bj[nt] = bias ? bias[nt * 16 + lm] : 0.f;
#pragma unroll
  for (int r = 0; r < 4; ++r) {
    size_t grow = (size_t)(row0 + w * 16 + lq * 4 + r) * DD;
#pragma unroll
    for (int nt = 0; nt < 8; ++nt) {
      float v = acc[nt][r] + bj[nt];
      if (RELU) v = fmaxf(v, 0.f);
      if (RES) v += res[grow + nt * 16 + lm];
      if (WF) out[grow + nt * 16 + lm] = v;
      if (WB) outb[grow + nt * 16 + lm] = f2bf(v);
    }
  }
}

// ---------------- aggregation: agg[i] = inv_deg[i] * sum_e relu(A[i] + B[src_e]) ----
// bf16 tables, fp32 accumulate; one wave per node, lane = 2 channels.

__global__ __launch_bounds__(256) void aggregate_bf16(
    const u16* __restrict__ A, const u16* __restrict__ B, const int* __restrict__ offs,
    const int* __restrict__ csr, const float* __restrict__ inv_deg, u16* __restrict__ agg) {
  int node = blockIdx.x * 4 + (threadIdx.x >> 6);
  int lane = threadIdx.x & 63;
  const int c = lane * 2;
  uint32_t au = *(const uint32_t*)(A + (size_t)node * DD + c);
  float ax = bflo2f(au), ay = bfhi2f(au);
  int beg = offs[node], end = offs[node + 1];
  float sx = 0.f, sy = 0.f;
  int e = beg;
  for (; e + 4 <= end; e += 4) {
    int s0 = csr[e + 0], s1 = csr[e + 1], s2 = csr[e + 2], s3 = csr[e + 3];
    uint32_t b0 = *(const uint32_t*)(B + (size_t)s0 * DD + c);
    uint32_t b1 = *(const uint32_t*)(B + (size_t)s1 * DD + c);
    uint32_t b2 = *(const uint32_t*)(B + (size_t)s2 * DD + c);
    uint32_t b3 = *(const uint32_t*)(B + (size_t)s3 * DD + c);
    sx += fmaxf(ax + bflo2f(b0), 0.f); sy += fmaxf(ay + bfhi2f(b0), 0.f);
    sx += fmaxf(ax + bflo2f(b1), 0.f); sy += fmaxf(ay + bfhi2f(b1), 0.f);
    sx += fmaxf(ax + bflo2f(b2), 0.f); sy += fmaxf(ay + bfhi2f(b2), 0.f);
    sx += fmaxf(ax + bflo2f(b3), 0.f); sy += fmaxf(ay + bfhi2f(b3), 0.f);
  }
  for (; e < end; ++e) {
    int s = csr[e];
    uint32_t b = *(const uint32_t*)(B + (size_t)s * DD + c);
    sx += fmaxf(ax + bflo2f(b), 0.f);
    sy += fmaxf(ay + bfhi2f(b), 0.f);
  }
  float wgt = inv_deg[node];
  uint32_t o = (uint32_t)f2bf(sx * wgt) | ((uint32_t)f2bf(sy * wgt) << 16);
  *(uint32_t*)(agg + (size_t)node * DD + c) = o;
}

// ---------------- launch ----------------

static inline char* align256(char* p) {
  return (char*)(((uintptr_t)p + 255) & ~(uintptr_t)255);
}

extern "C" void kernel_launch(void* const* d_in, const int* in_sizes, int n_in,
                              void* d_out, int out_size, void* d_ws, size_t ws_size,
                              hipStream_t stream) {
  const float* x_in  = (const float*)d_in[0];
  const int*   ei    = (const int*)d_in[1];
  const float* psi_w = (const float*)d_in[2];
  const float* psi_b = (const float*)d_in[3];
  const float* phi_w = (const float*)d_in[4];
  const float* phi_b = (const float*)d_in[5];
  const float* dp_w  = (const float*)d_in[6];
  const float* dp_b  = (const float*)d_in[7];
  float* out = (float*)d_out;

  const int* e_src = ei;
  const int* e_dst = ei + N_EDGES;

  const size_t NF = (size_t)N_NODES * DD;

  // workspace carve
  char* p = (char*)d_ws;
  int* deg = (int*)p;        p = align256(p + N_NODES * sizeof(int));
  int* cnt = (int*)p;        p = align256(p + N_NODES * sizeof(int));
  int* offs = (int*)p;       p = align256(p + (N_NODES + 1) * sizeof(int));
  int* csr = (int*)p;        p = align256(p + N_EDGES * sizeof(int));
  float* inv_deg = (float*)p; p = align256(p + N_NODES * sizeof(float));
  float* Xf0 = (float*)p;    p = align256(p + NF * sizeof(float));
  u16* xb0 = (u16*)p;        p = align256(p + NF * sizeof(u16));
  u16* xb1 = (u16*)p;        p = align256(p + NF * sizeof(u16));
  u16* Ab = (u16*)p;         p = align256(p + NF * sizeof(u16));
  u16* Bb = (u16*)p;         p = align256(p + NF * sizeof(u16));
  u16* aggb = (u16*)p;       p = align256(p + NF * sizeof(u16));
  u16* psiT = (u16*)p;       p = align256(p + 3 * 128 * 256 * sizeof(u16));
  u16* phiT = (u16*)p;       p = align256(p + 3 * 128 * 256 * sizeof(u16));
  u16* dpT = (u16*)p;        p = align256(p + 128 * 128 * sizeof(u16));

  hipMemsetAsync(deg, 0, N_NODES * sizeof(int), stream);
  hipMemsetAsync(cnt, 0, N_NODES * sizeof(int), stream);

  const int EB = 256;
  convert_x_kernel<<<(int)(NF / 8 / 256), 256, 0, stream>>>(x_in, xb0);
  convert_w_kernel<<<(212992 + 255) / 256, 256, 0, stream>>>(psi_w, phi_w, dp_w, psiT, phiT, dpT);
  count_deg_kernel<<<(N_EDGES + EB - 1) / EB, EB, 0, stream>>>(e_dst, deg);
  scan_kernel<<<1, 1024, 0, stream>>>(deg, offs);
  invdeg_kernel<<<(N_NODES + EB - 1) / EB, EB, 0, stream>>>(deg, inv_deg);
  fill_csr_kernel<<<(N_EDGES + EB - 1) / EB, EB, 0, stream>>>(e_src, e_dst, offs, cnt, csr);

  const int GB = N_NODES / 64;  // 625 blocks

  // fp32 residual chain: x_in -> Xf0 -> d_out -> Xf0 ; bf16 chain: xb0 -> xb1 -> xb0 -> xb1
  const float* resf[3] = {x_in, Xf0, out};
  float* outf[3] = {Xf0, out, Xf0};
  u16* xbc = xb0;
  u16* xbn = xb1;

  for (int l = 0; l < LAYERS; ++l) {
    const u16* pT = psiT + (size_t)l * 32768;
    // A = x @ psi_top + psi_b (bf16 out); B = x @ psi_bot (bf16 out)
    gemm_mfma<128, 256, false, false, false, true><<<GB, 256, 0, stream>>>(
        xbc, nullptr, pT, psi_b + l * DD, nullptr, nullptr, Ab);
    gemm_mfma<128, 256, false, false, false, true><<<GB, 256, 0, stream>>>(
        xbc, nullptr, pT + 128, nullptr, nullptr, nullptr, Bb);
    aggregate_bf16<<<N_NODES / 4, 256, 0, stream>>>(Ab, Bb, offs, csr, inv_deg, aggb);
    // new_x = relu(cat[x, agg] @ phi_w + phi_b) + x  -> fp32 + bf16
    gemm_mfma<256, 256, true, true, true, true><<<GB, 256, 0, stream>>>(
        xbc, aggb, phiT + (size_t)l * 32768, phi_b + l * DD, resf[l], outf[l], xbn);
    u16* t = xbc; xbc = xbn; xbn = t;
  }
  // final: out = x @ dp_w + dp_b (fp32 only)
  gemm_mfma<128, 128, false, false, true, false><<<GB, 256, 0, stream>>>(
      xbc, nullptr, dpT, dp_b, nullptr, out, nullptr);
}

// Round 3
// 330.467 us; speedup vs baseline: 1.8833x; 1.1755x over previous
//
#include <hip/hip_runtime.h>
#include <stdint.h>

#define N_NODES 40000
#define N_EDGES 640000
#define DD 128
#define LAYERS 3
#define SB 40  // scan blocks: 40 * 1024 >= N_NODES

typedef unsigned short u16;
typedef u16 u16x8 __attribute__((ext_vector_type(8)));
typedef short bf16x8 __attribute__((ext_vector_type(8)));
typedef float f32x4 __attribute__((ext_vector_type(4)));

__device__ inline u16 f2bf(float f) {  // RNE f32 -> bf16 (finite inputs)
  uint32_t u = __float_as_uint(f);
  return (u16)((u + 0x7fffu + ((u >> 16) & 1u)) >> 16);
}
__device__ inline float bflo2f(uint32_t u) { return __uint_as_float(u << 16); }
__device__ inline float bfhi2f(uint32_t u) { return __uint_as_float(u & 0xffff0000u); }

// ---------------- CSR build ----------------

__global__ void count_deg_kernel(const int* __restrict__ dst, int* __restrict__ deg) {
  int e = blockIdx.x * blockDim.x + threadIdx.x;
  if (e < N_EDGES) atomicAdd(&deg[dst[e]], 1);
}

__global__ __launch_bounds__(256) void deg_block_sum(const int* __restrict__ deg,
                                                     int* __restrict__ bsums) {
  __shared__ int red[256];
  int b = blockIdx.x, t = threadIdx.x;
  int idx = b * 1024 + t * 4;
  int s = 0;
  if (idx < N_NODES) {
    int4 v = *(const int4*)(deg + idx);
    s = v.x + v.y + v.z + v.w;
  }
  red[t] = s;
  __syncthreads();
  for (int o = 128; o > 0; o >>= 1) {
    if (t < o) red[t] += red[t + o];
    __syncthreads();
  }
  if (t == 0) bsums[b] = red[0];
}

__global__ __launch_bounds__(256) void scan_write(const int* __restrict__ deg,
                                                  const int* __restrict__ bsums,
                                                  int* __restrict__ offs,
                                                  float* __restrict__ inv_deg) {
  __shared__ int red[256];
  int b = blockIdx.x, t = threadIdx.x;
  // base = sum(bsums[0..b))
  red[t] = (t < b) ? bsums[t] : 0;
  __syncthreads();
  for (int o = 128; o > 0; o >>= 1) {
    if (t < o) red[t] += red[t + o];
    __syncthreads();
  }
  int base = red[0];
  __syncthreads();
  int idx = b * 1024 + t * 4;
  int4 v = {0, 0, 0, 0};
  if (idx < N_NODES) v = *(const int4*)(deg + idx);
  int ts = v.x + v.y + v.z + v.w;
  red[t] = ts;
  __syncthreads();
  for (int o = 1; o < 256; o <<= 1) {
    int u = (t >= o) ? red[t - o] : 0;
    __syncthreads();
    red[t] += u;
    __syncthreads();
  }
  int excl = base + red[t] - ts;
  if (idx < N_NODES) {
    int4 ov;
    ov.x = excl;
    ov.y = excl + v.x;
    ov.z = ov.y + v.y;
    ov.w = ov.z + v.z;
    *(int4*)(offs + idx) = ov;
    float4 iv;
    iv.x = 1.0f / (float)(v.x > 1 ? v.x : 1);
    iv.y = 1.0f / (float)(v.y > 1 ? v.y : 1);
    iv.z = 1.0f / (float)(v.z > 1 ? v.z : 1);
    iv.w = 1.0f / (float)(v.w > 1 ? v.w : 1);
    *(float4*)(inv_deg + idx) = iv;
  }
  if (b == SB - 1 && t == 255) offs[N_NODES] = base + red[255];
}

__global__ void fill_csr_kernel(const int* __restrict__ src, const int* __restrict__ dst,
                                const int* __restrict__ offs, int* __restrict__ cnt,
                                int* __restrict__ csr) {
  int e = blockIdx.x * blockDim.x + threadIdx.x;
  if (e < N_EDGES) {
    int d = dst[e];
    int pos = offs[d] + atomicAdd(&cnt[d], 1);
    csr[pos] = src[e];
  }
}

// ---------------- conversions ----------------

__global__ void convert_x_kernel(const float* __restrict__ x, u16* __restrict__ xb) {
  size_t i = (size_t)(blockIdx.x * blockDim.x + threadIdx.x) * 8;
  float4 v0 = *(const float4*)(x + i);
  float4 v1 = *(const float4*)(x + i + 4);
  u16x8 o;
  o[0] = f2bf(v0.x); o[1] = f2bf(v0.y); o[2] = f2bf(v0.z); o[3] = f2bf(v0.w);
  o[4] = f2bf(v1.x); o[5] = f2bf(v1.y); o[6] = f2bf(v1.z); o[7] = f2bf(v1.w);
  *(u16x8*)(xb + i) = o;
}

// psiF: [l][o=256][k=128]  (o<128: A col o, k-rows 0..127; o>=128: B col o-128, k-rows 128..255)
// phiT: [l][n=128][k=256]; dpT: [n=128][k=128]
__global__ void convert_w_kernel(const float* __restrict__ psi_w, const float* __restrict__ phi_w,
                                 const float* __restrict__ dp_w, u16* __restrict__ psiF,
                                 u16* __restrict__ phiT, u16* __restrict__ dpT) {
  int idx = blockIdx.x * blockDim.x + threadIdx.x;
  if (idx < 98304) {
    int l = idx >> 15, r = idx & 32767, o = r >> 7, k = r & 127;
    int kk = k + ((o >= 128) ? 128 : 0);
    psiF[idx] = f2bf(psi_w[l * 32768 + kk * 128 + (o & 127)]);
  } else if (idx < 196608) {
    int j = idx - 98304;
    int l = j >> 15, r = j & 32767, n = r >> 8, k = r & 255;
    phiT[j] = f2bf(phi_w[l * 32768 + k * 128 + n]);
  } else if (idx < 212992) {
    int j = idx - 196608;
    int n = j >> 7, k = j & 127;
    dpT[j] = f2bf(dp_w[k * 128 + n]);
  }
}

// ---------------- fused psi GEMM: [Ab | Bb] = X[Mx128] @ Wf[128x256] ----
// Block: 64 rows x 256 cols, 4 waves; wave w -> rows [w*16, w*16+16).

__global__ __launch_bounds__(256, 3) void gemm_psi(const u16* __restrict__ X0,
                                                   const u16* __restrict__ Wf,
                                                   const float* __restrict__ bias,
                                                   u16* __restrict__ Ab, u16* __restrict__ Bb) {
  __shared__ u16 Xs[64][72];
  __shared__ u16 Ws[256][72];
  const int tid = threadIdx.x;
  const int row0 = blockIdx.x * 64;
  const int w = tid >> 6, lane = tid & 63;
  const int lm = lane & 15, lq = lane >> 4;

  f32x4 acc[16];
#pragma unroll
  for (int i = 0; i < 16; ++i) acc[i] = (f32x4){0.f, 0.f, 0.f, 0.f};

#pragma unroll
  for (int c = 0; c < 2; ++c) {
#pragma unroll
    for (int i = 0; i < 2; ++i) {
      int fi = tid + i * 256;
      int r = fi >> 3, k8 = (fi & 7) * 8;
      *(u16x8*)&Xs[r][k8] = *(const u16x8*)(X0 + (size_t)(row0 + r) * DD + c * 64 + k8);
    }
#pragma unroll
    for (int i = 0; i < 8; ++i) {
      int fi = tid + i * 256;
      int n = fi >> 3, k8 = (fi & 7) * 8;
      *(u16x8*)&Ws[n][k8] = *(const u16x8*)(Wf + (size_t)n * 128 + c * 64 + k8);
    }
    __syncthreads();
#pragma unroll
    for (int ks = 0; ks < 2; ++ks) {
      bf16x8 a = *(const bf16x8*)&Xs[w * 16 + lm][lq * 8 + ks * 32];
#pragma unroll
      for (int nt = 0; nt < 16; ++nt) {
        bf16x8 b = *(const bf16x8*)&Ws[nt * 16 + lm][lq * 8 + ks * 32];
        acc[nt] = __builtin_amdgcn_mfma_f32_16x16x32_bf16(a, b, acc[nt], 0, 0, 0);
      }
    }
    __syncthreads();
  }

  float bj[8];
#pragma unroll
  for (int nt = 0; nt < 8; ++nt) bj[nt] = bias[nt * 16 + lm];
#pragma unroll
  for (int r = 0; r < 4; ++r) {
    size_t grow = (size_t)(row0 + w * 16 + lq * 4 + r) * DD;
#pragma unroll
    for (int nt = 0; nt < 8; ++nt) Ab[grow + nt * 16 + lm] = f2bf(acc[nt][r] + bj[nt]);
#pragma unroll
    for (int nt = 0; nt < 8; ++nt) Bb[grow + nt * 16 + lm] = f2bf(acc[nt + 8][r]);
  }
}

// ---------------- MFMA GEMM (phi / dp) ----------------

template <int K, int WS, bool RELU, bool RES, bool WF, bool WB>
__global__ __launch_bounds__(256, 4) void gemm_mfma(
    const u16* __restrict__ X0, const u16* __restrict__ X1, const u16* __restrict__ Wt,
    const float* __restrict__ bias, const float* __restrict__ res, float* __restrict__ out,
    u16* __restrict__ outb) {
  __shared__ u16 Xs[64][72];
  __shared__ u16 Ws[128][72];
  const int tid = threadIdx.x;
  const int row0 = blockIdx.x * 64;
  const int w = tid >> 6, lane = tid & 63;
  const int lm = lane & 15, lq = lane >> 4;

  f32x4 acc[8];
#pragma unroll
  for (int i = 0; i < 8; ++i) acc[i] = (f32x4){0.f, 0.f, 0.f, 0.f};

  const int NCH = K / 64;
#pragma unroll
  for (int c = 0; c < NCH; ++c) {
    const u16* Xsrc = (K == 256 && c >= 2) ? (X1 + (c - 2) * 64) : (X0 + c * 64);
#pragma unroll
    for (int i = 0; i < 2; ++i) {
      int fi = tid + i * 256;
      int r = fi >> 3, k8 = (fi & 7) * 8;
      *(u16x8*)&Xs[r][k8] = *(const u16x8*)(Xsrc + (size_t)(row0 + r) * DD + k8);
    }
#pragma unroll
    for (int i = 0; i < 4; ++i) {
      int fi = tid + i * 256;
      int n = fi >> 3, k8 = (fi & 7) * 8;
      *(u16x8*)&Ws[n][k8] = *(const u16x8*)(Wt + (size_t)n * WS + c * 64 + k8);
    }
    __syncthreads();
#pragma unroll
    for (int ks = 0; ks < 2; ++ks) {
      bf16x8 a = *(const bf16x8*)&Xs[w * 16 + lm][lq * 8 + ks * 32];
#pragma unroll
      for (int nt = 0; nt < 8; ++nt) {
        bf16x8 b = *(const bf16x8*)&Ws[nt * 16 + lm][lq * 8 + ks * 32];
        acc[nt] = __builtin_amdgcn_mfma_f32_16x16x32_bf16(a, b, acc[nt], 0, 0, 0);
      }
    }
    __syncthreads();
  }

  float bj[8];
#pragma unroll
  for (int nt = 0; nt < 8; ++nt) bj[nt] = bias ? bias[nt * 16 + lm] : 0.f;
#pragma unroll
  for (int r = 0; r < 4; ++r) {
    size_t grow = (size_t)(row0 + w * 16 + lq * 4 + r) * DD;
#pragma unroll
    for (int nt = 0; nt < 8; ++nt) {
      float v = acc[nt][r] + bj[nt];
      if (RELU) v = fmaxf(v, 0.f);
      if (RES) v += res[grow + nt * 16 + lm];
      if (WF) out[grow + nt * 16 + lm] = v;
      if (WB) outb[grow + nt * 16 + lm] = f2bf(v);
    }
  }
}

// ---------------- aggregation ----------------

__global__ __launch_bounds__(256) void aggregate_bf16(
    const u16* __restrict__ A, const u16* __restrict__ B, const int* __restrict__ offs,
    const int* __restrict__ csr, const float* __restrict__ inv_deg, u16* __restrict__ agg) {
  int node = blockIdx.x * 4 + (threadIdx.x >> 6);
  int lane = threadIdx.x & 63;
  const int c = lane * 2;
  uint32_t au = *(const uint32_t*)(A + (size_t)node * DD + c);
  float ax = bflo2f(au), ay = bfhi2f(au);
  int beg = offs[node], end = offs[node + 1];
  float sx = 0.f, sy = 0.f;
  int e = beg;
  for (; e + 4 <= end; e += 4) {
    int s0 = csr[e + 0], s1 = csr[e + 1], s2 = csr[e + 2], s3 = csr[e + 3];
    uint32_t b0 = *(const uint32_t*)(B + (size_t)s0 * DD + c);
    uint32_t b1 = *(const uint32_t*)(B + (size_t)s1 * DD + c);
    uint32_t b2 = *(const uint32_t*)(B + (size_t)s2 * DD + c);
    uint32_t b3 = *(const uint32_t*)(B + (size_t)s3 * DD + c);
    sx += fmaxf(ax + bflo2f(b0), 0.f); sy += fmaxf(ay + bfhi2f(b0), 0.f);
    sx += fmaxf(ax + bflo2f(b1), 0.f); sy += fmaxf(ay + bfhi2f(b1), 0.f);
    sx += fmaxf(ax + bflo2f(b2), 0.f); sy += fmaxf(ay + bfhi2f(b2), 0.f);
    sx += fmaxf(ax + bflo2f(b3), 0.f); sy += fmaxf(ay + bfhi2f(b3), 0.f);
  }
  for (; e < end; ++e) {
    int s = csr[e];
    uint32_t b = *(const uint32_t*)(B + (size_t)s * DD + c);
    sx += fmaxf(ax + bflo2f(b), 0.f);
    sy += fmaxf(ay + bfhi2f(b), 0.f);
  }
  float wgt = inv_deg[node];
  uint32_t o = (uint32_t)f2bf(sx * wgt) | ((uint32_t)f2bf(sy * wgt) << 16);
  *(uint32_t*)(agg + (size_t)node * DD + c) = o;
}

// ---------------- launch ----------------

static inline char* align256(char* p) {
  return (char*)(((uintptr_t)p + 255) & ~(uintptr_t)255);
}

extern "C" void kernel_launch(void* const* d_in, const int* in_sizes, int n_in,
                              void* d_out, int out_size, void* d_ws, size_t ws_size,
                              hipStream_t stream) {
  const float* x_in  = (const float*)d_in[0];
  const int*   ei    = (const int*)d_in[1];
  const float* psi_w = (const float*)d_in[2];
  const float* psi_b = (const float*)d_in[3];
  const float* phi_w = (const float*)d_in[4];
  const float* phi_b = (const float*)d_in[5];
  const float* dp_w  = (const float*)d_in[6];
  const float* dp_b  = (const float*)d_in[7];
  float* out = (float*)d_out;

  const int* e_src = ei;
  const int* e_dst = ei + N_EDGES;

  const size_t NF = (size_t)N_NODES * DD;

  char* p = (char*)d_ws;
  int* deg = (int*)p;        p = align256(p + N_NODES * sizeof(int));
  int* cnt = (int*)p;        p = align256(p + N_NODES * sizeof(int));
  int* offs = (int*)p;       p = align256(p + (N_NODES + 1) * sizeof(int));
  int* bsums = (int*)p;      p = align256(p + SB * sizeof(int));
  int* csr = (int*)p;        p = align256(p + N_EDGES * sizeof(int));
  float* inv_deg = (float*)p; p = align256(p + N_NODES * sizeof(float));
  float* Xf0 = (float*)p;    p = align256(p + NF * sizeof(float));
  u16* xb0 = (u16*)p;        p = align256(p + NF * sizeof(u16));
  u16* xb1 = (u16*)p;        p = align256(p + NF * sizeof(u16));
  u16* Ab = (u16*)p;         p = align256(p + NF * sizeof(u16));
  u16* Bb = (u16*)p;         p = align256(p + NF * sizeof(u16));
  u16* aggb = (u16*)p;       p = align256(p + NF * sizeof(u16));
  u16* psiF = (u16*)p;       p = align256(p + 3 * 256 * 128 * sizeof(u16));
  u16* phiT = (u16*)p;       p = align256(p + 3 * 128 * 256 * sizeof(u16));
  u16* dpT = (u16*)p;        p = align256(p + 128 * 128 * sizeof(u16));

  hipMemsetAsync(deg, 0, N_NODES * sizeof(int), stream);
  hipMemsetAsync(cnt, 0, N_NODES * sizeof(int), stream);

  const int EB = 256;
  convert_x_kernel<<<(int)(NF / 8 / 256), 256, 0, stream>>>(x_in, xb0);
  convert_w_kernel<<<(212992 + 255) / 256, 256, 0, stream>>>(psi_w, phi_w, dp_w, psiF, phiT, dpT);
  count_deg_kernel<<<(N_EDGES + EB - 1) / EB, EB, 0, stream>>>(e_dst, deg);
  deg_block_sum<<<SB, 256, 0, stream>>>(deg, bsums);
  scan_write<<<SB, 256, 0, stream>>>(deg, bsums, offs, inv_deg);
  fill_csr_kernel<<<(N_EDGES + EB - 1) / EB, EB, 0, stream>>>(e_src, e_dst, offs, cnt, csr);

  const int GB = N_NODES / 64;  // 625 blocks

  const float* resf[3] = {x_in, Xf0, out};
  float* outf[3] = {Xf0, out, Xf0};
  u16* xbc = xb0;
  u16* xbn = xb1;

  for (int l = 0; l < LAYERS; ++l) {
    gemm_psi<<<GB, 256, 0, stream>>>(xbc, psiF + (size_t)l * 32768, psi_b + l * DD, Ab, Bb);
    aggregate_bf16<<<N_NODES / 4, 256, 0, stream>>>(Ab, Bb, offs, csr, inv_deg, aggb);
    gemm_mfma<256, 256, true, true, true, true><<<GB, 256, 0, stream>>>(
        xbc, aggb, phiT + (size_t)l * 32768, phi_b + l * DD, resf[l], outf[l], xbn);
    u16* t = xbc; xbc = xbn; xbn = t;
  }
  gemm_mfma<128, 128, false, false, true, false><<<GB, 256, 0, stream>>>(
      xbc, nullptr, dpT, dp_b, nullptr, out, nullptr);
}